// Round 7
// baseline (106.985 us; speedup 1.0000x reference)
//
#include <hip/hip_runtime.h>

#define IS 256
#define FCOUNT 4096
#define NEARP 0.1f
#define FARP 100.0f
#define TINYF 1e-12f
#define CCAP 512         // per-coarse-bin (32x32 px) capacity: mean ~180, ~2.8x margin
#define CAP_T 320        // per-16x16-tile LDS pool (mean ~60; R2/R3/R4-proven)
#define GCAP 128         // per-image sliver-list capacity (R0-proven)
#define DET_GLOBAL 1e-5f // |det| below this -> per-image list (escape unbounded)
#define ZEPS 2e-4f       // early-z slack: zp >= min(z)-5e-5 proven; 4x margin

// Value barrier: pins a value in a VGPR; no transform across it.
__device__ __forceinline__ float frn(float r) { asm("" : "+v"(r)); return r; }
__device__ __forceinline__ float mulrn(float a, float b) { return frn(a * b); }
__device__ __forceinline__ float addrn(float a, float b) { return frn(a + b); }
__device__ __forceinline__ float subrn(float a, float b) { return frn(a - b); }
__device__ __forceinline__ float divrn(float a, float b) { return frn(a / b); }
__device__ __forceinline__ float fmarn(float a, float b, float c) {
    return frn(__builtin_fmaf(a, b, c));
}

// ---------------------------------------------------------------------------
// R7: hierarchical binning. R0-R6 post-mortem: every raster-side change was
// null; the never-touched bin_kernel is the structural pig — 1 wave/CU
// (occupancy 3%) x up to ~25 SERIAL device-scope atomicAdd->store round
// trips per lane (~800 cy each, nothing to hide them). Fix: bin to COARSE
// 32x32-px tiles (8x8 grid) -> regular faces (bbox <= 0.224 NDC < 32 px)
// span <= 2x2 tiles -> <= 4 atomics per lane. The raster block (16x16-px
// tile) then builds its fine pool from its coarse bin (~180 faces, ONE
// grid-stride pass over 256 threads) using the bbox stored in cD, and runs
// the R2-verified mask-scan + R3-verified saved-state shade from LDS.
// Coarse-rect formulas = R0-verified fine-bin formulas with divisor 16->64
// (offset 241->193): same exact-x2^8 arithmetic, same dilation>>rounding
// slack. Quadrant center-ranges are subsets of the coarse center-range, so
// any face overlapping a quadrant is present in the coarse bin. Pool/list
// orders arbitrary — argmin tie-break order-independent (since R0).
// ---------------------------------------------------------------------------

// ---------- pass 1: per-face constants + bbox + coarse 8x8 binning ----------
__global__ __launch_bounds__(64) void bin_kernel(
    const float* __restrict__ faces,
    float4* __restrict__ cA, float4* __restrict__ cB, float4* __restrict__ cC,
    float4* __restrict__ cD,
    int* __restrict__ ccnt, int* __restrict__ clist,
    int* __restrict__ gcount, int* __restrict__ glist, int B, int F)
{
    const int lane = threadIdx.x;           // block = 1 wave
    const int base = blockIdx.x * 64;       // face-group base in [0, B*F)
    const int gid  = base + lane;
    if (gid >= B * F) return;               // B*F % 64 == 0: never splits a wave
    const int b = gid >> 12, f = gid & (FCOUNT - 1);   // F == 4096

    __shared__ float4 stage4[144];          // 576 floats = 64 faces
    float* stage = (float*)stage4;
    const float* src = faces + (size_t)base * 9;   // 16B-aligned (base%64==0)
    const float4* s4 = (const float4*)src;
    stage4[lane]      = s4[lane];
    stage4[64 + lane] = s4[64 + lane];
    stage[512 + lane] = src[512 + lane];
    __builtin_amdgcn_wave_barrier();        // order LDS write -> read (free)

    const float* fp = stage + lane * 9;     // stride-9 words: 2-way = free
    const float x0 = fp[0], y0 = fp[1], z0 = fp[2];
    const float x1 = fp[3], y1 = fp[4], z1 = fp[5];
    const float x2 = fp[6], y2 = fp[7], z2 = fp[8];

    // Verified contracted numerics: C = fma(xa, yb, -(xb*ya)).
    const float A0 = subrn(x2, x1), B0 = subrn(y1, y2);
    const float C0 = fmarn(x1, y2, -mulrn(x2, y1));
    const float A1 = subrn(x0, x2), B1 = subrn(y2, y0);
    const float C1 = fmarn(x2, y0, -mulrn(x0, y2));
    const float A2 = subrn(x1, x0), B2 = subrn(y0, y1);
    const float C2 = fmarn(x0, y1, -mulrn(x1, y0));
    cA[gid] = make_float4(A0, B0, C0, A1);
    cB[gid] = make_float4(B1, C1, A2, B2);
    cC[gid] = make_float4(C2, z0, z1, z2);

    const float det = (x1 - x0) * (y2 - y0) - (x2 - x0) * (y1 - y0);
    const float ad = fabsf(det);
    if (ad < DET_GLOBAL) {
        // Sliver: unbounded fp escape -> per-image list (R0-proven). Excluded
        // from coarse bins, so no duplicates in the raster pool.
        const int pos = atomicAdd(&gcount[b], 1);
        if (pos < GCAP) glist[b * GCAP + pos] = f;
        return;
    }
    // Escape bound: fp-inside region extends <= ~6e-8/|det| beyond the hull;
    // dilate 2e-3 + 3e-7/|det| (5x safety, <= 0.032).
    const float d = 2e-3f + 3e-7f / ad;
    const float lox = fminf(x0, fminf(x1, x2)) - d;
    const float hix = fmaxf(x0, fmaxf(x1, x2)) + d;
    const float loy = fminf(y0, fminf(y1, y2)) - d;
    const float hiy = fmaxf(y0, fmaxf(y1, y2)) + d;
    cD[gid] = make_float4(lox, hix, loy, hiy);

    // Coarse 32x32-px tile c covers centers xp in
    // [(64c+1-256)/256, (64c+63-256)/256]. Overlap (exact arith):
    // c >= (256*lox+193)/64 and c <= (256*hix+255)/64 — the R0-verified
    // fine-bin formulas with divisor 16->64. Dilation (>=2e-3 NDC = 0.5 px)
    // dwarfs the ~2^-15 fp slack of these bounds (same proof as R0).
    int cx0 = (int)ceilf ((256.f * lox + 193.f) * (1.f / 64.f));
    int cx1 = (int)floorf((256.f * hix + 255.f) * (1.f / 64.f));
    int cy0 = (int)ceilf ((256.f * loy + 193.f) * (1.f / 64.f));
    int cy1 = (int)floorf((256.f * hiy + 255.f) * (1.f / 64.f));
    cx0 = max(cx0, 0); cx1 = min(cx1, 7);
    cy0 = max(cy0, 0); cy1 = min(cy1, 7);
    // Regular faces span <= 2x2 coarse tiles -> <= 4 serial atomics.
    for (int cy = cy0; cy <= cy1; ++cy)
        for (int cx = cx0; cx <= cx1; ++cx) {
            const int t = (b * 8 + cy) * 8 + cx;
            const int pos = atomicAdd(&ccnt[t], 1);
            if (pos < CCAP) clist[(size_t)t * CCAP + pos] = f;
        }
}

// ---------- pass 2: rasterize — one 256-thr block per 16x16-px tile ---------
__global__ __launch_bounds__(256, 4) void raster_kernel(
    const float* __restrict__ textures,
    const float4* __restrict__ cA, const float4* __restrict__ cB,
    const float4* __restrict__ cC, const float4* __restrict__ cD,
    const int* __restrict__ ccnt, const int* __restrict__ clist,
    const int* __restrict__ gcount, const int* __restrict__ glist,
    float* __restrict__ out, int B, int F)
{
    const int tid  = threadIdx.x;
    const int lane = tid & 63;
    const int w    = tid >> 6;
    const int b    = blockIdx.x >> 8;
    const int tile = blockIdx.x & 255;
    const int TX   = tile & 15;        // 16-px tile coords (0..15)
    const int TY   = tile >> 4;
    const int cbin = (b * 8 + (TY >> 1)) * 8 + (TX >> 1);   // coarse bin

    __shared__ float4 s_a[CAP_T];
    __shared__ float4 s_b[CAP_T];
    __shared__ float4 s_c[CAP_T];
    __shared__ int    s_i[CAP_T];      // f | (quadmask << 12)
    __shared__ int    s_cnt;

    if (tid == 0) s_cnt = 0;
    __syncthreads();

    // Quadrant pixel-center ranges (exact floats: small ints / 2^8) —
    // identical to the old 8x8 bin ranges (R2-proven). Each is a subset of
    // the coarse tile's center range, so coarse membership is implied.
    const float qxlo0 = (float)(32 * TX +  1 - 256) * (1.0f / 256.0f);
    const float qxhi0 = (float)(32 * TX + 15 - 256) * (1.0f / 256.0f);
    const float qxlo1 = (float)(32 * TX + 17 - 256) * (1.0f / 256.0f);
    const float qxhi1 = (float)(32 * TX + 31 - 256) * (1.0f / 256.0f);
    const float qylo0 = (float)(32 * TY +  1 - 256) * (1.0f / 256.0f);
    const float qyhi0 = (float)(32 * TY + 15 - 256) * (1.0f / 256.0f);
    const float qylo1 = (float)(32 * TY + 17 - 256) * (1.0f / 256.0f);
    const float qyhi1 = (float)(32 * TY + 31 - 256) * (1.0f / 256.0f);

    const int ccount = min(ccnt[cbin], CCAP);
    const int gcnt   = min(gcount[b], GCAP);
    const int* cl    = clist + (size_t)cbin * CCAP;
    const int* gl    = glist + b * GCAP;
    const int  fb    = b * F;

    // ---- phase A: build fine pool from the coarse bin (~180 faces, one
    // grid-stride pass). Bbox compares are the R2-verified quadrant tests on
    // the bit-identical stored bbox (cD computed with the same ops). --------
    for (int k = tid; k < ccount; k += 256) {
        const int f = cl[k];
        const float4 bb = cD[fb + f];   // (lox, hix, loy, hiy)
        const bool ox0 = (bb.y >= qxlo0) && (bb.x <= qxhi0);
        const bool ox1 = (bb.y >= qxlo1) && (bb.x <= qxhi1);
        const bool oy0 = (bb.w >= qylo0) && (bb.z <= qyhi0);
        const bool oy1 = (bb.w >= qylo1) && (bb.z <= qyhi1);
        const int mask = ((ox0 && oy0) ? 1 : 0) | ((ox1 && oy0) ? 2 : 0)
                       | ((ox0 && oy1) ? 4 : 0) | ((ox1 && oy1) ? 8 : 0);
        if (mask) {
            const int pos = atomicAdd(&s_cnt, 1);
            if (pos < CAP_T) {
                s_a[pos] = cA[fb + f];
                s_b[pos] = cB[fb + f];
                s_c[pos] = cC[fb + f];
                s_i[pos] = f | (mask << 12);
            }
        }
    }
    // Slivers: scanned by every quadrant (R0 semantics), mask 0xF.
    for (int k = tid; k < gcnt; k += 256) {
        const int f = gl[k];
        const int pos = atomicAdd(&s_cnt, 1);
        if (pos < CAP_T) {
            s_a[pos] = cA[fb + f];
            s_b[pos] = cB[fb + f];
            s_c[pos] = cC[fb + f];
            s_i[pos] = f | (0xF << 12);
        }
    }
    __syncthreads();
    const int cnt = min(s_cnt, CAP_T);

    // ---- phase B: rasterize — wave w owns one 8x8 quadrant (R2-verified) --
    const int qtx = 2 * TX + (w & 1);
    const int qty = 2 * TY + (w >> 1);
    const int px  = qtx * 8 + (lane & 7);
    const int py  = qty * 8 + (lane >> 3);
    const float xp = (float)(2 * px + 1 - IS) * (1.0f / IS);  // exact (/2^8)
    const float yp = (float)(2 * py + 1 - IS) * (1.0f / IS);  // exact
    const int qbit = 1 << (12 + w);

    float bestz = FARP;
    int   besti = -1;
    float bn0 = 0.f, bn1 = 0.f, bn2 = 0.f;     // winner's normalized weights
    float bz0 = 1.f, bz1 = 1.f, bz2 = 1.f;     // winner's vertex depths

    for (int j = 0; j < cnt; ++j) {
        const int mi = s_i[j];
        if (!(mi & qbit)) continue;          // wave-uniform skip
        const float4 fa  = s_a[j];
        const float4 fb4 = s_b[j];
        const float4 fc  = s_c[j];
        // Contracted: w = fma(yp, A, xp*B) + C  (verified chain)
        const float w0 = addrn(fmarn(yp, fa.x, mulrn(xp, fa.y)), fa.z);
        const float w1 = addrn(fmarn(yp, fa.w, mulrn(xp, fb4.x)), fb4.y);
        const float w2 = addrn(fmarn(yp, fb4.z, mulrn(xp, fb4.w)), fc.x);
        const float det = addrn(addrn(w0, w1), w2);
        bool ins;
        if (det > TINYF)       ins = (w0 > 0.f) && (w1 > 0.f) && (w2 > 0.f);
        else if (det < -TINYF) ins = (w0 < 0.f) && (w1 < 0.f) && (w2 < 0.f);
        else                   ins = false;
        // Early-z: zp >= min(z) - ~5e-5, so minz > bestz+ZEPS cannot win/tie.
        const float minz = fminf(fminf(fc.y, fc.z), fc.w);
        if (ins && minz <= bestz + ZEPS) {
            float n0 = divrn(w0, det), n1 = divrn(w1, det), n2 = divrn(w2, det);
            n0 = frn(fminf(fmaxf(n0, 0.f), 1.f));
            n1 = frn(fminf(fmaxf(n1, 0.f), 1.f));
            n2 = frn(fminf(fmaxf(n2, 0.f), 1.f));
            float s = addrn(addrn(n0, n1), n2);
            s = (s > TINYF) ? s : 1.0f;
            n0 = divrn(n0, s); n1 = divrn(n1, s); n2 = divrn(n2, s);
            float iz = addrn(addrn(divrn(n0, fc.y), divrn(n1, fc.z)),
                             divrn(n2, fc.w));
            iz = (fabsf(iz) > TINYF) ? iz : 1.0f;
            const float zp = divrn(1.0f, iz);
            if (zp > NEARP && zp < FARP) {
                const int fi = mi & 0xFFF;
                if (zp < bestz || (zp == bestz && fi < besti)) {
                    bestz = zp;
                    besti = fi;
                    bn0 = n0; bn1 = n1; bn2 = n2;
                    bz0 = fc.y; bz1 = fc.z; bz2 = fc.w;
                }
            }
        }
    }

    // ---- phase C: shade from saved phase-B state (R3-verified) ------------
    float r = 0.f, g = 0.f, bch = 0.f, alpha = 0.f, depth = FARP;
    if (besti >= 0) {
        const float zp = bestz;
        depth = zp;
        const float t0 = fminf(fmaxf(divrn(mulrn(mulrn(bn0, 3.0f), zp), bz0), 0.f), 2.999f);
        const float t1 = fminf(fmaxf(divrn(mulrn(mulrn(bn1, 3.0f), zp), bz1), 0.f), 2.999f);
        const float t2 = fminf(fmaxf(divrn(mulrn(mulrn(bn2, 3.0f), zp), bz2), 0.f), 2.999f);
        const float l0 = floorf(t0), l1 = floorf(t1), l2 = floorf(t2);
        const float fr0 = subrn(t0, l0), fr1 = subrn(t1, l1), fr2 = subrn(t2, l2);
        const int i0 = (int)l0, i1 = (int)l1, i2 = (int)l2;

        const float* txp = textures + (size_t)(b * F + besti) * 64 * 3;
        for (int d0 = 0; d0 < 2; ++d0)
            for (int d1 = 0; d1 < 2; ++d1)
                for (int d2 = 0; d2 < 2; ++d2) {
                    const float wg = mulrn(mulrn(d0 ? fr0 : subrn(1.0f, fr0),
                                                 d1 ? fr1 : subrn(1.0f, fr1)),
                                           d2 ? fr2 : subrn(1.0f, fr2));
                    const float* tp = txp + ((i0 + d0) * 16 + (i1 + d1) * 4 + (i2 + d2)) * 3;
                    r   = addrn(r,   mulrn(wg, tp[0]));
                    g   = addrn(g,   mulrn(wg, tp[1]));
                    bch = addrn(bch, mulrn(wg, tp[2]));
                }
        alpha = 1.0f;
    }

    float* op = out + (((size_t)b * IS + py) * IS + px) * 5;
    op[0] = r;
    op[1] = g;
    op[2] = bch;
    op[3] = alpha;
    op[4] = depth;
}

extern "C" void kernel_launch(void* const* d_in, const int* in_sizes, int n_in,
                              void* d_out, int out_size, void* d_ws, size_t ws_size,
                              hipStream_t stream) {
    const float* faces    = (const float*)d_in[0];
    const float* textures = (const float*)d_in[1];
    float* out = (float*)d_out;
    const int F = FCOUNT;
    const int B = in_sizes[0] / (F * 9);
    const int ncoarse = B * 64;          // 8x8 coarse bins per image

    int* ccnt   = (int*)d_ws;                         // ncoarse ints
    int* gcount = ccnt + ncoarse;                     // B ints (contiguous for memset)
    int* glist  = gcount + B;                         // B*GCAP ints
    int* clist  = glist + B * GCAP;                   // ncoarse*CCAP ints
    float4* cA  = (float4*)(clist + (size_t)ncoarse * CCAP);  // B*F float4
    float4* cB  = cA + (size_t)B * F;
    float4* cC  = cB + (size_t)B * F;
    float4* cD  = cC + (size_t)B * F;

    hipMemsetAsync(ccnt, 0, (size_t)(ncoarse + B) * sizeof(int), stream);
    bin_kernel<<<dim3((B * F + 63) / 64), dim3(64), 0, stream>>>(
        faces, cA, cB, cC, cD, ccnt, clist, gcount, glist, B, F);
    raster_kernel<<<dim3(B * 256), dim3(256), 0, stream>>>(
        textures, cA, cB, cC, cD, ccnt, clist, gcount, glist, out, B, F);
}

// Round 8
// 96.367 us; speedup vs baseline: 1.1102x; 1.1102x over previous
//
#include <hip/hip_runtime.h>

#define IS 256
#define FCOUNT 4096
#define NEARP 0.1f
#define FARP 100.0f
#define TINYF 1e-12f
#define CAP_T 320        // per-16x16-tile LDS list capacity (mean ~60; >5x margin)
#define DET_GLOBAL 1e-5f // |det| below this -> treat as covering all quadrants
#define ZEPS 2e-4f       // early-z slack: zp >= min(z)-5e-5 proven; 4x margin

// Value barrier: pins a value in a VGPR; no transform across it.
__device__ __forceinline__ float frn(float r) { asm("" : "+v"(r)); return r; }
__device__ __forceinline__ float mulrn(float a, float b) { return frn(a * b); }
__device__ __forceinline__ float addrn(float a, float b) { return frn(a + b); }
__device__ __forceinline__ float subrn(float a, float b) { return frn(a - b); }
__device__ __forceinline__ float divrn(float a, float b) { return frn(a / b); }
__device__ __forceinline__ float fmarn(float a, float b, float c) {
    return frn(__builtin_fmaf(a, b, c));
}

// ---------------------------------------------------------------------------
// R8 = exact revert to the R2 kernel (best measured: 96.9 us, passed).
// R0-R7 ledger: kernel-interior work varied >=4x across 7 structures while
// dur_us stayed 96.9-107 -> dur_us is dominated by a fixed ~97 us harness
// floor (256 MiB workspace poison fill at ~42 us / 80% HBM peak + graph
// replay overhead). The R2 single-dispatch structure is the empirical
// optimum; later "improvements" only added dispatches or noise.
//
// Single-kernel rasterizer, NO global binning pass, NO grid sync, NO
// workspace. Each block (one 16x16-px tile) derives its own bin locally:
// scan all F faces of its image (147 KB, L2-resident; 16 faces/thread),
// dilated-bbox test vs the block's 4 8x8 quadrants, append {constants,
// f | quadmask} to an LDS list. One __syncthreads(), then the verified
// raster/shade chain; wave w skips faces without quadrant bit w. Numerics
// bit-identical to the R0-passing kernel: same contracted chains on same
// inputs; quadrant overlap ranges reproduce the per-8x8-bin ranges exactly;
// slivers (|det|<1e-5) get mask 0xF (= scanned-by-all semantics); tie-break
// (zp, then smaller index) is order-independent.
// LDS: 320*(48+4)+4 ~= 16.7 KB -> 4 blocks/CU.
// ---------------------------------------------------------------------------
__global__ __launch_bounds__(256, 4) void fused_raster(
    const float* __restrict__ faces,
    const float* __restrict__ textures,
    float* __restrict__ out, int B, int F)
{
    const int tid  = threadIdx.x;
    const int lane = tid & 63;
    const int w    = tid >> 6;
    const int b    = blockIdx.x >> 8;
    const int tile = blockIdx.x & 255;
    const int TX   = tile & 15;        // 16-px tile coords (0..15)
    const int TY   = tile >> 4;

    __shared__ float4 s_a[CAP_T];
    __shared__ float4 s_b[CAP_T];
    __shared__ float4 s_c[CAP_T];
    __shared__ int    s_i[CAP_T];      // f | (quadmask << 12)
    __shared__ int    s_cnt;

    if (tid == 0) s_cnt = 0;
    __syncthreads();

    // Quadrant pixel-center ranges (exact floats: small ints / 2^8).
    // Quadrant qx covers px in [16TX+8qx, 16TX+8qx+7], xp = (2px+1-256)/256,
    // i.e. xp in [(32TX+16qx+1-256)/256, (32TX+16qx+15-256)/256] — identical
    // to the old 8x8 bin t=2TX+qx ranges.
    const float qxlo0 = (float)(32 * TX +  1 - 256) * (1.0f / 256.0f);
    const float qxhi0 = (float)(32 * TX + 15 - 256) * (1.0f / 256.0f);
    const float qxlo1 = (float)(32 * TX + 17 - 256) * (1.0f / 256.0f);
    const float qxhi1 = (float)(32 * TX + 31 - 256) * (1.0f / 256.0f);
    const float qylo0 = (float)(32 * TY +  1 - 256) * (1.0f / 256.0f);
    const float qyhi0 = (float)(32 * TY + 15 - 256) * (1.0f / 256.0f);
    const float qylo1 = (float)(32 * TY + 17 - 256) * (1.0f / 256.0f);
    const float qyhi1 = (float)(32 * TY + 31 - 256) * (1.0f / 256.0f);

    // ---- phase A: local bin — scan all faces of image b -------------------
    // Escape bound: fp-inside region extends <= ~6e-8/|det| beyond the hull;
    // dilate 2e-3 + 3e-7/|det| (5x safety, <= 0.032). |det| < 1e-5 ->
    // unbounded escape -> conservatively cover all 4 quadrants.
    const float* fimg = faces + (size_t)b * F * 9;
    for (int f = tid; f < F; f += 256) {
        const float* fp = fimg + (size_t)f * 9;
        const float x0 = fp[0], y0 = fp[1], z0 = fp[2];
        const float x1 = fp[3], y1 = fp[4], z1 = fp[5];
        const float x2 = fp[6], y2 = fp[7], z2 = fp[8];

        const float det = (x1 - x0) * (y2 - y0) - (x2 - x0) * (y1 - y0);
        const float ad = fabsf(det);
        int mask;
        if (ad < DET_GLOBAL) {
            mask = 0xF;
        } else {
            const float d = 2e-3f + 3e-7f / ad;   // <= 0.032
            const float lox = fminf(x0, fminf(x1, x2)) - d;
            const float hix = fmaxf(x0, fmaxf(x1, x2)) + d;
            const float loy = fminf(y0, fminf(y1, y2)) - d;
            const float hiy = fmaxf(y0, fmaxf(y1, y2)) + d;
            // Dilation d (>= 2e-3 = 0.5 NDC px) dwarfs the ~1e-7 fp slack of
            // these compares (same argument as the old ceil/floor bin bounds).
            const bool ox0 = (hix >= qxlo0) && (lox <= qxhi0);
            const bool ox1 = (hix >= qxlo1) && (lox <= qxhi1);
            const bool oy0 = (hiy >= qylo0) && (loy <= qyhi0);
            const bool oy1 = (hiy >= qylo1) && (loy <= qyhi1);
            mask = ((ox0 && oy0) ? 1 : 0) | ((ox1 && oy0) ? 2 : 0)
                 | ((ox0 && oy1) ? 4 : 0) | ((ox1 && oy1) ? 8 : 0);
        }
        if (mask) {
            // Verified contracted numerics: C = fma(xa, yb, -(xb*ya)).
            const float A0 = subrn(x2, x1), B0 = subrn(y1, y2);
            const float C0 = fmarn(x1, y2, -mulrn(x2, y1));
            const float A1 = subrn(x0, x2), B1 = subrn(y2, y0);
            const float C1 = fmarn(x2, y0, -mulrn(x0, y2));
            const float A2 = subrn(x1, x0), B2 = subrn(y0, y1);
            const float C2 = fmarn(x0, y1, -mulrn(x1, y0));
            const int pos = atomicAdd(&s_cnt, 1);
            if (pos < CAP_T) {
                s_a[pos] = make_float4(A0, B0, C0, A1);
                s_b[pos] = make_float4(B1, C1, A2, B2);
                s_c[pos] = make_float4(C2, z0, z1, z2);
                s_i[pos] = f | (mask << 12);
            }
        }
    }
    __syncthreads();
    const int cnt = min(s_cnt, CAP_T);

    // ---- phase B: rasterize — wave w owns one 8x8 quadrant ----------------
    // Early-z: skip the 10-divide chain when min(z) > bestz + ZEPS (cannot win
    // or tie). Numerics: verified contracted chain; tie-break (zp, then
    // smaller index) matches the reference's chunked argmin regardless of
    // list order.
    const int qtx = 2 * TX + (w & 1);
    const int qty = 2 * TY + (w >> 1);
    const int px  = qtx * 8 + (lane & 7);
    const int py  = qty * 8 + (lane >> 3);
    const float xp = (float)(2 * px + 1 - IS) * (1.0f / IS);  // exact (/2^8)
    const float yp = (float)(2 * py + 1 - IS) * (1.0f / IS);  // exact
    const int qbit = 1 << (12 + w);

    float bestz = FARP;
    int   besti = -1;

    for (int j = 0; j < cnt; ++j) {
        const int mi = s_i[j];
        if (!(mi & qbit)) continue;          // wave-uniform skip
        const float4 fa  = s_a[j];
        const float4 fb4 = s_b[j];
        const float4 fc  = s_c[j];
        // Contracted: w = fma(yp, A, xp*B) + C
        const float w0 = addrn(fmarn(yp, fa.x, mulrn(xp, fa.y)), fa.z);
        const float w1 = addrn(fmarn(yp, fa.w, mulrn(xp, fb4.x)), fb4.y);
        const float w2 = addrn(fmarn(yp, fb4.z, mulrn(xp, fb4.w)), fc.x);
        const float det = addrn(addrn(w0, w1), w2);
        bool ins;
        if (det > TINYF)       ins = (w0 > 0.f) && (w1 > 0.f) && (w2 > 0.f);
        else if (det < -TINYF) ins = (w0 < 0.f) && (w1 < 0.f) && (w2 < 0.f);
        else                   ins = false;
        // Early-z: zp >= min(z) - ~5e-5 (clipped weights sum ~1), so a face
        // with min(z) > bestz+ZEPS can neither win nor tie.
        const float minz = fminf(fminf(fc.y, fc.z), fc.w);
        if (ins && minz <= bestz + ZEPS) {
            float n0 = divrn(w0, det), n1 = divrn(w1, det), n2 = divrn(w2, det);
            n0 = frn(fminf(fmaxf(n0, 0.f), 1.f));
            n1 = frn(fminf(fmaxf(n1, 0.f), 1.f));
            n2 = frn(fminf(fmaxf(n2, 0.f), 1.f));
            float s = addrn(addrn(n0, n1), n2);
            s = (s > TINYF) ? s : 1.0f;
            n0 = divrn(n0, s); n1 = divrn(n1, s); n2 = divrn(n2, s);
            float iz = addrn(addrn(divrn(n0, fc.y), divrn(n1, fc.z)),
                             divrn(n2, fc.w));
            iz = (fabsf(iz) > TINYF) ? iz : 1.0f;
            const float zp = divrn(1.0f, iz);
            if (zp > NEARP && zp < FARP) {
                const int fi = mi & 0xFFF;
                if (zp < bestz || (zp == bestz && fi < besti)) {
                    bestz = zp;
                    besti = fi;
                }
            }
        }
    }

    // ---- phase C: shade the winning face (verified chain, unchanged) ------
    float r = 0.f, g = 0.f, bch = 0.f, alpha = 0.f, depth = FARP;
    if (besti >= 0) {
        const float* fp = fimg + (size_t)besti * 9;
        const float x0 = fp[0], y0 = fp[1], z0 = fp[2];
        const float x1 = fp[3], y1 = fp[4], z1 = fp[5];
        const float x2 = fp[6], y2 = fp[7], z2 = fp[8];
        const float w0 = addrn(fmarn(yp, subrn(x2, x1), mulrn(xp, subrn(y1, y2))),
                               fmarn(x1, y2, -mulrn(x2, y1)));
        const float w1 = addrn(fmarn(yp, subrn(x0, x2), mulrn(xp, subrn(y2, y0))),
                               fmarn(x2, y0, -mulrn(x0, y2)));
        const float w2 = addrn(fmarn(yp, subrn(x1, x0), mulrn(xp, subrn(y0, y1))),
                               fmarn(x0, y1, -mulrn(x1, y0)));
        const float det = addrn(addrn(w0, w1), w2);
        const float sd = (fabsf(det) > TINYF) ? det : 1.0f;
        float n0 = divrn(w0, sd), n1 = divrn(w1, sd), n2 = divrn(w2, sd);
        n0 = frn(fminf(fmaxf(n0, 0.f), 1.f));
        n1 = frn(fminf(fmaxf(n1, 0.f), 1.f));
        n2 = frn(fminf(fmaxf(n2, 0.f), 1.f));
        float s = addrn(addrn(n0, n1), n2);
        s = (s > TINYF) ? s : 1.0f;
        n0 = divrn(n0, s); n1 = divrn(n1, s); n2 = divrn(n2, s);
        float iz = addrn(addrn(divrn(n0, z0), divrn(n1, z1)), divrn(n2, z2));
        iz = (fabsf(iz) > TINYF) ? iz : 1.0f;
        const float zp = divrn(1.0f, iz);
        depth = zp;

        const float t0 = fminf(fmaxf(divrn(mulrn(mulrn(n0, 3.0f), zp), z0), 0.f), 2.999f);
        const float t1 = fminf(fmaxf(divrn(mulrn(mulrn(n1, 3.0f), zp), z1), 0.f), 2.999f);
        const float t2 = fminf(fmaxf(divrn(mulrn(mulrn(n2, 3.0f), zp), z2), 0.f), 2.999f);
        const float l0 = floorf(t0), l1 = floorf(t1), l2 = floorf(t2);
        const float fr0 = subrn(t0, l0), fr1 = subrn(t1, l1), fr2 = subrn(t2, l2);
        const int i0 = (int)l0, i1 = (int)l1, i2 = (int)l2;

        const float* tx = textures + (size_t)(b * F + besti) * 64 * 3;
        for (int d0 = 0; d0 < 2; ++d0)
            for (int d1 = 0; d1 < 2; ++d1)
                for (int d2 = 0; d2 < 2; ++d2) {
                    const float wg = mulrn(mulrn(d0 ? fr0 : subrn(1.0f, fr0),
                                                 d1 ? fr1 : subrn(1.0f, fr1)),
                                           d2 ? fr2 : subrn(1.0f, fr2));
                    const float* tp = tx + ((i0 + d0) * 16 + (i1 + d1) * 4 + (i2 + d2)) * 3;
                    r   = addrn(r,   mulrn(wg, tp[0]));
                    g   = addrn(g,   mulrn(wg, tp[1]));
                    bch = addrn(bch, mulrn(wg, tp[2]));
                }
        alpha = 1.0f;
    }

    float* op = out + (((size_t)b * IS + py) * IS + px) * 5;
    op[0] = r;
    op[1] = g;
    op[2] = bch;
    op[3] = alpha;
    op[4] = depth;
}

extern "C" void kernel_launch(void* const* d_in, const int* in_sizes, int n_in,
                              void* d_out, int out_size, void* d_ws, size_t ws_size,
                              hipStream_t stream) {
    const float* faces    = (const float*)d_in[0];
    const float* textures = (const float*)d_in[1];
    float* out = (float*)d_out;
    const int F = FCOUNT;
    const int B = in_sizes[0] / (F * 9);

    fused_raster<<<dim3(B * 256), dim3(256), 0, stream>>>(
        faces, textures, out, B, F);
}

// Round 9
// 94.651 us; speedup vs baseline: 1.1303x; 1.0181x over previous
//
#include <hip/hip_runtime.h>

#define IS 256
#define FCOUNT 4096
#define NEARP 0.1f
#define FARP 100.0f
#define TINYF 1e-12f
#define CAP_T 320        // per-16x16-tile LDS list capacity (mean ~60; >5x margin)
#define DET_GLOBAL 1e-5f // |det| below this -> treat as covering all quadrants
#define ZEPS 2e-4f       // early-z slack: zp >= min(z)-5e-5 proven; 4x margin

// Value barrier: pins a value in a VGPR; no transform across it.
__device__ __forceinline__ float frn(float r) { asm("" : "+v"(r)); return r; }
__device__ __forceinline__ float mulrn(float a, float b) { return frn(a * b); }
__device__ __forceinline__ float addrn(float a, float b) { return frn(a + b); }
__device__ __forceinline__ float subrn(float a, float b) { return frn(a - b); }
__device__ __forceinline__ float divrn(float a, float b) { return frn(a / b); }
__device__ __forceinline__ float fmarn(float a, float b, float c) {
    return frn(__builtin_fmaf(a, b, c));
}

// ---------------------------------------------------------------------------
// R9 = R2 fused single-dispatch structure (best measured, 96.4 us) with the
// one lever never isolated in it: wave-level parallelism. R8 counters:
// VALUBusy 46%, Occ 26%, HBM 4% -> kernel is stall/latency-limited at
// 4 waves/SIMD (1024 blocks x 256 thr == residency). Now 512-thr blocks
// (launch_bounds(512,8) -> 32 waves/CU = 8 waves/SIMD): wave = (quadrant q,
// stripe s); each quadrant's LDS list is scanned by 2 waves (entries
// j % 2 == s, per-wave serial length ~32), exact per-stripe partial argmin
// (early-z bound is absolute, so per-stripe culling stays exact), then a
// per-pixel lexicographic (z, smaller idx) merge — the R6-verified merge =
// the reference tie-break; stripe partition of an order-independent argmin
// is exact. Stripe-0 keeps its partial in registers; only stripe-1 publishes
// through LDS. Phase A aggregate cost unchanged (512 thr x 8 iters).
// Accept-path numerics: the verified frn-pinned chains, op-for-op.
// LDS: 16,644 (pool) + 8,192 (stripe-1 partials) ~= 24.8 KB -> 4 blocks/CU.
// ---------------------------------------------------------------------------
__global__ __launch_bounds__(512, 8) void fused_raster(
    const float* __restrict__ faces,
    const float* __restrict__ textures,
    float* __restrict__ out, int B, int F)
{
    const int tid  = threadIdx.x;
    const int lane = tid & 63;
    const int w    = tid >> 6;         // 0..7
    const int q    = w & 3;            // quadrant within the 16x16 tile
    const int st   = w >> 2;           // stripe 0/1 of the face list
    const int b    = blockIdx.x >> 8;
    const int tile = blockIdx.x & 255;
    const int TX   = tile & 15;        // 16-px tile coords (0..15)
    const int TY   = tile >> 4;

    __shared__ float4 s_a[CAP_T];
    __shared__ float4 s_b[CAP_T];
    __shared__ float4 s_c[CAP_T];
    __shared__ int    s_i[CAP_T];      // f | (quadmask << 12)
    __shared__ int    s_cnt;
    // Stripe-1 partials (stripe-0 keeps its own in registers):
    __shared__ float  s_pz[4][64];
    __shared__ int    s_pi[4][64];
    __shared__ float  s_pn[4][64][3];
    __shared__ float  s_pvz[4][64][3];

    if (tid == 0) s_cnt = 0;
    __syncthreads();

    // Quadrant pixel-center ranges (exact floats: small ints / 2^8) —
    // identical to the original per-8x8-bin ranges (proven since R0).
    const float qxlo0 = (float)(32 * TX +  1 - 256) * (1.0f / 256.0f);
    const float qxhi0 = (float)(32 * TX + 15 - 256) * (1.0f / 256.0f);
    const float qxlo1 = (float)(32 * TX + 17 - 256) * (1.0f / 256.0f);
    const float qxhi1 = (float)(32 * TX + 31 - 256) * (1.0f / 256.0f);
    const float qylo0 = (float)(32 * TY +  1 - 256) * (1.0f / 256.0f);
    const float qyhi0 = (float)(32 * TY + 15 - 256) * (1.0f / 256.0f);
    const float qylo1 = (float)(32 * TY + 17 - 256) * (1.0f / 256.0f);
    const float qyhi1 = (float)(32 * TY + 31 - 256) * (1.0f / 256.0f);

    // ---- phase A: local bin — scan all faces of image b (R2-verified) -----
    // Escape bound: fp-inside region extends <= ~6e-8/|det| beyond the hull;
    // dilate 2e-3 + 3e-7/|det| (5x safety, <= 0.032). |det| < 1e-5 ->
    // unbounded escape -> conservatively cover all 4 quadrants.
    const float* fimg = faces + (size_t)b * F * 9;
    for (int f = tid; f < F; f += 512) {
        const float* fp = fimg + (size_t)f * 9;
        const float x0 = fp[0], y0 = fp[1], z0 = fp[2];
        const float x1 = fp[3], y1 = fp[4], z1 = fp[5];
        const float x2 = fp[6], y2 = fp[7], z2 = fp[8];

        const float det = (x1 - x0) * (y2 - y0) - (x2 - x0) * (y1 - y0);
        const float ad = fabsf(det);
        int mask;
        if (ad < DET_GLOBAL) {
            mask = 0xF;
        } else {
            const float d = 2e-3f + 3e-7f / ad;   // <= 0.032
            const float lox = fminf(x0, fminf(x1, x2)) - d;
            const float hix = fmaxf(x0, fmaxf(x1, x2)) + d;
            const float loy = fminf(y0, fminf(y1, y2)) - d;
            const float hiy = fmaxf(y0, fmaxf(y1, y2)) + d;
            // Dilation d (>= 2e-3 = 0.5 NDC px) dwarfs the ~1e-7 fp slack of
            // these compares (same argument as the ceil/floor bin bounds).
            const bool ox0 = (hix >= qxlo0) && (lox <= qxhi0);
            const bool ox1 = (hix >= qxlo1) && (lox <= qxhi1);
            const bool oy0 = (hiy >= qylo0) && (loy <= qyhi0);
            const bool oy1 = (hiy >= qylo1) && (loy <= qyhi1);
            mask = ((ox0 && oy0) ? 1 : 0) | ((ox1 && oy0) ? 2 : 0)
                 | ((ox0 && oy1) ? 4 : 0) | ((ox1 && oy1) ? 8 : 0);
        }
        if (mask) {
            // Verified contracted numerics: C = fma(xa, yb, -(xb*ya)).
            const float A0 = subrn(x2, x1), B0 = subrn(y1, y2);
            const float C0 = fmarn(x1, y2, -mulrn(x2, y1));
            const float A1 = subrn(x0, x2), B1 = subrn(y2, y0);
            const float C1 = fmarn(x2, y0, -mulrn(x0, y2));
            const float A2 = subrn(x1, x0), B2 = subrn(y0, y1);
            const float C2 = fmarn(x0, y1, -mulrn(x1, y0));
            const int pos = atomicAdd(&s_cnt, 1);
            if (pos < CAP_T) {
                s_a[pos] = make_float4(A0, B0, C0, A1);
                s_b[pos] = make_float4(B1, C1, A2, B2);
                s_c[pos] = make_float4(C2, z0, z1, z2);
                s_i[pos] = f | (mask << 12);
            }
        }
    }
    __syncthreads();
    const int cnt = min(s_cnt, CAP_T);

    // ---- phase B: wave (q, st) scans stripe st of quadrant q's list -------
    const int qtx = 2 * TX + (q & 1);
    const int qty = 2 * TY + (q >> 1);
    const int px  = qtx * 8 + (lane & 7);
    const int py  = qty * 8 + (lane >> 3);
    const float xp = (float)(2 * px + 1 - IS) * (1.0f / IS);  // exact (/2^8)
    const float yp = (float)(2 * py + 1 - IS) * (1.0f / IS);  // exact
    const int qbit = 1 << (12 + q);

    float bestz = FARP;
    int   besti = -1;
    float bn0 = 0.f, bn1 = 0.f, bn2 = 0.f;     // winner's normalized weights
    float bz0 = 1.f, bz1 = 1.f, bz2 = 1.f;     // winner's vertex depths

    for (int j = st; j < cnt; j += 2) {
        const int mi = s_i[j];
        if (!(mi & qbit)) continue;          // wave-uniform skip
        const float4 fa  = s_a[j];
        const float4 fb4 = s_b[j];
        const float4 fc  = s_c[j];
        // Contracted: w = fma(yp, A, xp*B) + C  (verified chain)
        const float w0 = addrn(fmarn(yp, fa.x, mulrn(xp, fa.y)), fa.z);
        const float w1 = addrn(fmarn(yp, fa.w, mulrn(xp, fb4.x)), fb4.y);
        const float w2 = addrn(fmarn(yp, fb4.z, mulrn(xp, fb4.w)), fc.x);
        const float det = addrn(addrn(w0, w1), w2);
        bool ins;
        if (det > TINYF)       ins = (w0 > 0.f) && (w1 > 0.f) && (w2 > 0.f);
        else if (det < -TINYF) ins = (w0 < 0.f) && (w1 < 0.f) && (w2 < 0.f);
        else                   ins = false;
        // Early-z: zp >= min(z) - ~5e-5 (absolute bound), so a face with
        // min(z) > bestz+ZEPS can neither win nor tie — exact per stripe.
        const float minz = fminf(fminf(fc.y, fc.z), fc.w);
        if (ins && minz <= bestz + ZEPS) {
            float n0 = divrn(w0, det), n1 = divrn(w1, det), n2 = divrn(w2, det);
            n0 = frn(fminf(fmaxf(n0, 0.f), 1.f));
            n1 = frn(fminf(fmaxf(n1, 0.f), 1.f));
            n2 = frn(fminf(fmaxf(n2, 0.f), 1.f));
            float s = addrn(addrn(n0, n1), n2);
            s = (s > TINYF) ? s : 1.0f;
            n0 = divrn(n0, s); n1 = divrn(n1, s); n2 = divrn(n2, s);
            float iz = addrn(addrn(divrn(n0, fc.y), divrn(n1, fc.z)),
                             divrn(n2, fc.w));
            iz = (fabsf(iz) > TINYF) ? iz : 1.0f;
            const float zp = divrn(1.0f, iz);
            if (zp > NEARP && zp < FARP) {
                const int fi = mi & 0xFFF;
                if (zp < bestz || (zp == bestz && fi < besti)) {
                    bestz = zp;
                    besti = fi;
                    bn0 = n0; bn1 = n1; bn2 = n2;
                    bz0 = fc.y; bz1 = fc.z; bz2 = fc.w;
                }
            }
        }
    }

    // Stripe 1 publishes its partial; stripe 0 merges in registers.
    if (st == 1) {
        s_pz[q][lane] = bestz;
        s_pi[q][lane] = besti;
        s_pn[q][lane][0]  = bn0; s_pn[q][lane][1]  = bn1; s_pn[q][lane][2]  = bn2;
        s_pvz[q][lane][0] = bz0; s_pvz[q][lane][1] = bz1; s_pvz[q][lane][2] = bz2;
    }
    __syncthreads();

    // ---- phase C: stripe-0 waves merge + shade (R6-verified merge:
    // lexicographic (z, smaller idx) = reference tie-break; empty partial is
    // (FARP,-1) and any real winner has z < FARP strictly). Shade from the
    // winning partial's saved state (R3-verified: bit-identical n*,z*,zp). --
    if (st == 0) {
        const float z1p = s_pz[q][lane];
        const int   i1p = s_pi[q][lane];
        if (z1p < bestz || (z1p == bestz && i1p < besti)) {
            bestz = z1p;
            besti = i1p;
            bn0 = s_pn[q][lane][0]; bn1 = s_pn[q][lane][1]; bn2 = s_pn[q][lane][2];
            bz0 = s_pvz[q][lane][0]; bz1 = s_pvz[q][lane][1]; bz2 = s_pvz[q][lane][2];
        }

        float r = 0.f, g = 0.f, bch = 0.f, alpha = 0.f, depth = FARP;
        if (besti >= 0) {
            const float zp = bestz;
            depth = zp;
            const float t0 = fminf(fmaxf(divrn(mulrn(mulrn(bn0, 3.0f), zp), bz0), 0.f), 2.999f);
            const float t1 = fminf(fmaxf(divrn(mulrn(mulrn(bn1, 3.0f), zp), bz1), 0.f), 2.999f);
            const float t2 = fminf(fmaxf(divrn(mulrn(mulrn(bn2, 3.0f), zp), bz2), 0.f), 2.999f);
            const float l0 = floorf(t0), l1 = floorf(t1), l2 = floorf(t2);
            const float fr0 = subrn(t0, l0), fr1 = subrn(t1, l1), fr2 = subrn(t2, l2);
            const int i0 = (int)l0, i1 = (int)l1, i2 = (int)l2;

            const float* txp = textures + (size_t)(b * F + besti) * 64 * 3;
            for (int d0 = 0; d0 < 2; ++d0)
                for (int d1 = 0; d1 < 2; ++d1)
                    for (int d2 = 0; d2 < 2; ++d2) {
                        const float wg = mulrn(mulrn(d0 ? fr0 : subrn(1.0f, fr0),
                                                     d1 ? fr1 : subrn(1.0f, fr1)),
                                               d2 ? fr2 : subrn(1.0f, fr2));
                        const float* tp = txp + ((i0 + d0) * 16 + (i1 + d1) * 4 + (i2 + d2)) * 3;
                        r   = addrn(r,   mulrn(wg, tp[0]));
                        g   = addrn(g,   mulrn(wg, tp[1]));
                        bch = addrn(bch, mulrn(wg, tp[2]));
                    }
            alpha = 1.0f;
        }

        float* op = out + (((size_t)b * IS + py) * IS + px) * 5;
        op[0] = r;
        op[1] = g;
        op[2] = bch;
        op[3] = alpha;
        op[4] = depth;
    }
}

extern "C" void kernel_launch(void* const* d_in, const int* in_sizes, int n_in,
                              void* d_out, int out_size, void* d_ws, size_t ws_size,
                              hipStream_t stream) {
    const float* faces    = (const float*)d_in[0];
    const float* textures = (const float*)d_in[1];
    float* out = (float*)d_out;
    const int F = FCOUNT;
    const int B = in_sizes[0] / (F * 9);

    fused_raster<<<dim3(B * 256), dim3(512), 0, stream>>>(
        faces, textures, out, B, F);
}